// Round 15
// baseline (247.547 us; speedup 1.0000x reference)
//
#include <hip/hip_runtime.h>

#define SDIM 2048
#define DDIM 1024
#define NH 16
#define DK 64
#define NB 2
#define MROWS (NB * SDIM) // 4096
#define MAXEV 65536
#define EXPC 0.18033688011112f // 0.125 * log2(e), folded into Q at projection
#define L01 -3.3219281f        // log2(0.1)

typedef _Float16 f16x8 __attribute__((ext_vector_type(8)));
typedef _Float16 f16x4 __attribute__((ext_vector_type(4)));
typedef float f32x4 __attribute__((ext_vector_type(4)));

__device__ __forceinline__ void ld_lds16(const _Float16* g, _Float16* l) {
  __builtin_amdgcn_global_load_lds(
      (const __attribute__((address_space(1))) void*)g,
      (__attribute__((address_space(3))) void*)l, 16, 0, 0);
}

// ---------- K0: fp32 -> fp16 convert, all four arrays in one launch ----------
__global__ __launch_bounds__(256) void cvt_f16(
    const float* __restrict__ x, const float* __restrict__ wq,
    const float* __restrict__ wk, const float* __restrict__ wv,
    _Float16* __restrict__ xh, _Float16* __restrict__ wqh,
    _Float16* __restrict__ wkh, _Float16* __restrict__ wvh) {
  int i = blockIdx.x * 256 + threadIdx.x; // float4 index
  const float* src;
  _Float16* dst;
  int off;
  if (i < 1048576) {
    src = x; dst = xh; off = i;
  } else if (i < 1310720) {
    src = wq; dst = wqh; off = i - 1048576;
  } else if (i < 1572864) {
    src = wk; dst = wkh; off = i - 1310720;
  } else {
    src = wv; dst = wvh; off = i - 1572864;
  }
  float4 v = ((const float4*)src)[off];
  f16x4 h;
  h[0] = (_Float16)v.x; h[1] = (_Float16)v.y;
  h[2] = (_Float16)v.z; h[3] = (_Float16)v.w;
  ((f16x4*)dst)[off] = h;
}

// ---------- K1: fused QKV projection, fp16 MFMA, 128x128 tile, BK=64.
// K-loop = r10 form (16KB sA/sB, two __syncthreads per K-step) +
// LDS-transpose epilogue -> full-128B-line stores (r13). Q pre-scaled. ----------
__global__ __launch_bounds__(256, 2) void proj_gemm(
    const _Float16* __restrict__ xh, const _Float16* __restrict__ Wqh,
    const _Float16* __restrict__ Wkh, const _Float16* __restrict__ Wvh,
    const float* __restrict__ bq, const float* __restrict__ bk,
    const float* __restrict__ bv, _Float16* __restrict__ Qo,
    _Float16* __restrict__ Ko, float* __restrict__ Vo) {
  // 33.8KB union: K-loop uses first 32KB as sA/sB; epilogue reuses as Tb
  __shared__ __align__(16) _Float16 SMEM[16896];
  _Float16* sA = SMEM;
  _Float16* sB = SMEM + 128 * 64;
  const int t = threadIdx.x;
  const int lane = t & 63, wv = t >> 6;
  const int lr = lane & 15, quad = lane >> 4;
  const int wm = wv >> 1, wn = wv & 1;
  const int m0 = blockIdx.y * 128, n0 = blockIdx.x * 128;
  const int z = blockIdx.z;
  const _Float16* Bp = z == 0 ? Wqh : (z == 1 ? Wkh : Wvh);
  const float* bias = z == 0 ? bq : (z == 1 ? bk : bv);

  const int strow = t >> 3;            // 0..31 per issue
  const int stchunk = t & 7;           // phys chunk
  const int stsrc = (stchunk ^ (strow & 7)) * 8; // src col (halfs)

  f32x4 acc[4][4];
#pragma unroll
  for (int i = 0; i < 4; ++i)
#pragma unroll
    for (int j = 0; j < 4; ++j) acc[i][j] = (f32x4){0.f, 0.f, 0.f, 0.f};

  for (int k0 = 0; k0 < DDIM; k0 += 64) {
    __syncthreads(); // prior LDS reads complete
#pragma unroll
    for (int i = 0; i < 4; ++i) {
      const int row = i * 32 + strow;
      ld_lds16(&xh[(size_t)(m0 + row) * DDIM + k0 + stsrc],
               &sA[row * 64 + stchunk * 8]);
      ld_lds16(&Bp[(size_t)(n0 + row) * DDIM + k0 + stsrc],
               &sB[row * 64 + stchunk * 8]);
    }
    __syncthreads(); // drains vmcnt: LDS visible
    f16x8 af[4][2], bf[4][2];
#pragma unroll
    for (int i = 0; i < 4; ++i)
#pragma unroll
      for (int kk = 0; kk < 2; ++kk) {
        const int ph = ((kk * 4 + quad) ^ (lr & 7)) * 8;
        af[i][kk] = *(const f16x8*)&sA[(wm * 64 + i * 16 + lr) * 64 + ph];
        bf[i][kk] = *(const f16x8*)&sB[(wn * 64 + i * 16 + lr) * 64 + ph];
      }
#pragma unroll
    for (int kk = 0; kk < 2; ++kk)
#pragma unroll
      for (int i = 0; i < 4; ++i)
#pragma unroll
        for (int j = 0; j < 4; ++j)
          acc[i][j] = __builtin_amdgcn_mfma_f32_16x16x32_f16(
              af[i][kk], bf[j][kk], acc[i][j], 0, 0, 0);
  }

  // ---- epilogue: LDS transpose -> full-line stores ----
  const int h0 = n0 >> 6;   // n-tile covers heads h0, h0+1
  const int bb = m0 >> 11;  // batch (tiles never straddle batches)
  const int s0 = m0 & 2047;
  __syncthreads(); // K-loop LDS reads done; SMEM reusable
  if (z < 2) {
    _Float16* dst = z == 0 ? Qo : Ko;
    _Float16* Tb = SMEM; // 64 rows x 136 halfs (padded) = 17.4KB
    const float scl = z == 0 ? EXPC : 1.0f;
#pragma unroll 1
    for (int p = 0; p < 2; ++p) {
      if (wm == p) {
#pragma unroll
        for (int j = 0; j < 4; ++j) {
          const int ng = wn * 64 + j * 16 + lr;
          const float bvv = bias[n0 + ng];
#pragma unroll
          for (int i = 0; i < 4; ++i)
#pragma unroll
            for (int r = 0; r < 4; ++r) {
              const int row = i * 16 + quad * 4 + r; // 0..63
              Tb[row * 136 + ng] = (_Float16)((acc[i][j][r] + bvv) * scl);
            }
        }
      }
      __syncthreads();
      // 4 issues x (16 rows x 16 lanes x 16B): each row = 2 full 128B lines
      const int srow = t >> 4, scc = t & 15;
#pragma unroll
      for (int ii = 0; ii < 4; ++ii) {
        const int row = ii * 16 + srow;
        const int s = s0 + p * 64 + row;
        const int h = h0 + (scc >> 3);
        const int d = (scc & 7) * 8;
        f16x8 v = *(const f16x8*)&Tb[row * 136 + scc * 8];
        *(f16x8*)&dst[((size_t)(bb * NH + h) * SDIM + s) * DK + d] = v;
      }
      __syncthreads();
    }
  } else {
    float* Tb = (float*)SMEM; // 64 rows x 132 floats (padded) = 33.8KB
#pragma unroll 1
    for (int p = 0; p < 2; ++p) {
      if (wm == p) {
#pragma unroll
        for (int j = 0; j < 4; ++j) {
          const int ng = wn * 64 + j * 16 + lr;
          const float bvv = bias[n0 + ng];
#pragma unroll
          for (int i = 0; i < 4; ++i)
#pragma unroll
            for (int r = 0; r < 4; ++r) {
              const int row = i * 16 + quad * 4 + r;
              Tb[row * 132 + ng] = acc[i][j][r] + bvv;
            }
        }
      }
      __syncthreads();
      // 8 issues x (8 rows x 32 lanes x 16B): each row = 4 full 128B lines
      const int srow = t >> 5, scc = t & 31;
#pragma unroll
      for (int ii = 0; ii < 8; ++ii) {
        const int row = ii * 8 + srow;
        const int s = s0 + p * 64 + row;
        const int h = h0 + (scc >> 4);
        const int d = (scc & 15) * 4;
        float4 v = *(const float4*)&Tb[row * 132 + scc * 4];
        *(float4*)&Vo[((size_t)(bb * NH + h) * SDIM + s) * DK + d] = v;
      }
      __syncthreads();
    }
  }
}

// ---------- K2: la = -log2(sum_k 2^(Q'.K)) per row. r15 restructure: each
// wave computes ALL 64 q-rows x its OWN 32-key quarter of the 128-key
// stage (was: 16 q-rows x all 128 keys). Q is loop-invariant -> lives in
// registers (8 x f16x8, loaded once); B-fragments are reused across the 4
// q-blocks -> ds_read_b128 per stage per wave drops 16 -> 4 (kills the 4x
// LDS-read amplification: 16KB read per 16KB staged instead of 64KB).
// Same proven 16x16x32 fragment/swizzle patterns; 3-ring + counted
// vmcnt(4) + setprio unchanged. Tail: 16-lane shfl reduce + cross-wave
// LDS combine (runs once). ----------
__global__ __launch_bounds__(256, 3) void attn_denom(
    const _Float16* __restrict__ Q, const _Float16* __restrict__ K,
    float* __restrict__ laOut) {
  __shared__ __align__(16) _Float16 KS[3 * 8192]; // 48KB: 3 x 128x64 K tiles
  __shared__ float red[4][64];                    // 1KB cross-wave partials
  const int t = threadIdx.x;
  const int lane = t & 63, wave = t >> 6;
  const int quad = lane >> 4, lr = lane & 15;
  const int id = blockIdx.x;
  const int xcd = id & 7, inner = id >> 3; // inner in [0,128)
  const int bh = xcd * 4 + (inner >> 5);
  const int q0 = (inner & 31) * 64;
  const _Float16* Qh = Q + (size_t)bh * SDIM * DK;
  const _Float16* Kh = K + (size_t)bh * SDIM * DK;
  const int strow = t >> 3, stchunk = t & 7;
  const int stsrc = (stchunk ^ (strow & 7)) * 8;
  const int ph0 = (quad ^ (lr & 7)) * 8;
  const int ph1 = ((4 + quad) ^ (lr & 7)) * 8;

  // Q preload: 4 q-blocks x 2 d-chunks, loop-invariant (32 VGPR)
  f16x8 qf[4][2];
#pragma unroll
  for (int qb = 0; qb < 4; ++qb)
#pragma unroll
    for (int ch = 0; ch < 2; ++ch)
      qf[qb][ch] = *(const f16x8*)&Qh[(size_t)(q0 + qb * 16 + lr) * DK +
                                      ch * 32 + quad * 8];

#define STAGE_DN(KP, BUF)                                                  \
  {                                                                        \
    _Pragma("unroll") for (int i = 0; i < 4; ++i)                          \
        ld_lds16(&(KP)[(size_t)(i * 32 + strow) * DK + stsrc],             \
                 &(BUF)[(i * 32 + strow) * 64 + stchunk * 8]);             \
  }

  // wave owns keys [wave*32, wave*32+32): 2 k-blocks of 16. B-frag (b0,b1)
  // shared across the 4 q-block MFMAs.
#define COMPUTE_DN(BUF)                                                    \
  _Pragma("unroll") for (int kb = 0; kb < 2; ++kb) {                       \
    const int key = wave * 32 + kb * 16 + lr;                              \
    f16x8 b0 = *(const f16x8*)&(BUF)[key * 64 + ph0];                      \
    f16x8 b1 = *(const f16x8*)&(BUF)[key * 64 + ph1];                      \
    _Pragma("unroll") for (int qb = 0; qb < 4; ++qb) {                     \
      f32x4 acc = {0.f, 0.f, 0.f, 0.f};                                    \
      acc = __builtin_amdgcn_mfma_f32_16x16x32_f16(qf[qb][0], b0, acc, 0,  \
                                                   0, 0);                  \
      acc = __builtin_amdgcn_mfma_f32_16x16x32_f16(qf[qb][1], b1, acc, 0,  \
                                                   0, 0);                  \
      _Pragma("unroll") for (int r = 0; r < 4; ++r)                        \
          dsum[qb][r] += __builtin_amdgcn_exp2f(acc[r]);                   \
    }                                                                      \
  }

  float dsum[4][4] = {};
  const _Float16* kp = Kh; // loop-carried stage pointer
  STAGE_DN(kp, KS);
  kp += 128 * DK;
  int cb = 0;
#pragma unroll 1
  for (int kt = 0; kt < 16; ++kt) {
    const int nb_ = cb == 2 ? 0 : cb + 1;
    if (kt + 1 < 16) {
      STAGE_DN(kp, KS + nb_ * 8192);
      kp += 128 * DK;
    }
    asm volatile("" ::: "memory");
    if (kt + 1 < 16)
      asm volatile("s_waitcnt vmcnt(4)" ::: "memory"); // stage kt landed
    else
      asm volatile("s_waitcnt vmcnt(0)" ::: "memory");
    __builtin_amdgcn_s_barrier();
    asm volatile("" ::: "memory");
    __builtin_amdgcn_s_setprio(1);
    COMPUTE_DN(KS + cb * 8192);
    __builtin_amdgcn_s_setprio(0);
    cb = nb_;
  }
#undef STAGE_DN
#undef COMPUTE_DN

  // reduce over the 16 key-columns held across lr lanes (per quad)
#pragma unroll
  for (int m = 1; m < 16; m <<= 1)
#pragma unroll
    for (int qb = 0; qb < 4; ++qb)
#pragma unroll
      for (int r = 0; r < 4; ++r)
        dsum[qb][r] += __shfl_xor(dsum[qb][r], m, 64);
  if (lr == 0) {
#pragma unroll
    for (int qb = 0; qb < 4; ++qb)
#pragma unroll
      for (int r = 0; r < 4; ++r)
        red[wave][qb * 16 + quad * 4 + r] = dsum[qb][r];
  }
  __syncthreads();
  if (t < 64) {
    const float s = red[0][t] + red[1][t] + red[2][t] + red[3][t];
    laOut[(size_t)bh * SDIM + q0 + t] = -__builtin_amdgcn_logf(s); // -log2
  }
}

// ---------- K3: att_sum dense. r11/r14 form (best measured, 51.5us):
// 4-buffer ring, 1-head stages, K-DMA issued 2 STAGES AHEAD (Q/la 1
// ahead); steady vmcnt(10), final vmcnt(6). 32KB LDS -> 4 blocks/CU.
// Diet: la in MFMA C operand, max3 chains, pointer bumps, setprio. K
// L2-resident via XCD swizzle (FETCH=16.7MB); attMask sparse (cold path,
// pre-memset); attSum epilogue: LDS transpose -> full-128B-line nt stores. ----------
__global__ __launch_bounds__(256, 4) void attn_pass2(
    const _Float16* __restrict__ Q, const _Float16* __restrict__ K,
    const float* __restrict__ la, float* __restrict__ attSum,
    float* __restrict__ attMask, float4* __restrict__ ev,
    int* __restrict__ ecnt) {
  __shared__ __align__(16) _Float16 KS[4 * 4096]; // 32KB: 4 x 1-head tiles
  float* Tbuf = (float*)KS;                       // epilogue alias (17.4KB)
  const int t = threadIdx.x;
  const int lane = t & 63, wave = t >> 6;
  const int quad = lane >> 4, lr = lane & 15;
  // XCD swizzle: 2048 blocks, id%8 = XCD. Each XCD: one batch half-quadrant
  // (16 q0-tiles x 16 k0-tiles), k0 fastest within.
  const int id = blockIdx.x;
  const int xcd = id & 7, inner = id >> 3; // inner in [0,256)
  const int b = xcd >> 2;
  const int q0 = (((xcd >> 1) & 1) * 16 + (inner >> 4)) * 64;
  const int k0 = ((xcd & 1) * 16 + (inner & 15)) * 64;
  const int strow = t >> 3, stchunk = t & 7;
  const int stsrc = (stchunk ^ (strow & 7)) * 8;
  const int ph0 = (quad ^ (lr & 7)) * 8;
  const int ph1 = ((4 + quad) ^ (lr & 7)) * 8;

  const size_t qbase = ((size_t)(b * NH) * SDIM + q0 + wave * 16 + lr) * DK;
  const size_t dbase = (size_t)(b * NH) * SDIM + q0 + wave * 16 + quad * 4;
  const size_t hstep = (size_t)SDIM * DK;

  float asum[4][4] = {};
  float mx01 = -1e30f, mx23 = -1e30f; // 2 fused max chains

  f16x8 a0c, a1c, a0n, a1n;
  float4 lavc, lavn;

#define STAGE1(KP, BUF)                                                      \
  {                                                                          \
    _Pragma("unroll") for (int i = 0; i < 2; ++i)                            \
        ld_lds16(&(KP)[(size_t)(i * 32 + strow) * DK + stsrc],               \
                 &(BUF)[(i * 32 + strow) * 64 + stchunk * 8]);               \
  }

#define LOADQ1(QP, LAP, A0, A1, LV)                                          \
  {                                                                          \
    A0 = *(const f16x8*)&(QP)[quad * 8];                                     \
    A1 = *(const f16x8*)&(QP)[32 + quad * 8];                                \
    LV = *(const float4*)(LAP);                                              \
  }

#define COMPUTE1(BUF, A0, A1, LV)                                            \
  {                                                                          \
    const f32x4 cinit = {LV.x, LV.y, LV.z, LV.w};                            \
    _Pragma("unroll") for (int c = 0; c < 4; ++c) {                          \
      f16x8 b0 = *(const f16x8*)&(BUF)[(c * 16 + lr) * 64 + ph0];            \
      f16x8 b1 = *(const f16x8*)&(BUF)[(c * 16 + lr) * 64 + ph1];            \
      f32x4 acc = cinit; /* la folded into MFMA C operand */                 \
      acc = __builtin_amdgcn_mfma_f32_16x16x32_f16(A0, b0, acc, 0, 0, 0);    \
      acc = __builtin_amdgcn_mfma_f32_16x16x32_f16(A1, b1, acc, 0, 0, 0);    \
      mx01 = fmaxf(fmaxf(acc[0], acc[1]), mx01); /* v_max3 */                \
      mx23 = fmaxf(fmaxf(acc[2], acc[3]), mx23);                             \
      asum[c][0] += __builtin_amdgcn_exp2f(acc[0]);                          \
      asum[c][1] += __builtin_amdgcn_exp2f(acc[1]);                          \
      asum[c][2] += __builtin_amdgcn_exp2f(acc[2]);                          \
      asum[c][3] += __builtin_amdgcn_exp2f(acc[3]);                          \
    }                                                                        \
  }

  const _Float16* kp = K + (size_t)(b * NH) * hstep + (size_t)k0 * DK;
  const _Float16* qp = Q + qbase;
  const float* lap = la + dbase;
  STAGE1(kp, KS);          // stage 0 -> buf 0
  kp += hstep;
  STAGE1(kp, KS + 4096);   // stage 1 -> buf 1
  kp += hstep;
  LOADQ1(qp, lap, a0c, a1c, lavc);
  qp += hstep; lap += SDIM;
  int cb = 0;
#pragma unroll 1
  for (int h = 0; h < NH; ++h) {
    if (h + 2 < NH) {
      STAGE1(kp, KS + ((cb + 2) & 3) * 4096);
      kp += hstep;
    }
    if (h + 1 < NH) {
      LOADQ1(qp, lap, a0n, a1n, lavn);
      qp += hstep; lap += SDIM;
    }
    asm volatile("" ::: "memory");
    if (h == NH - 1)
      asm volatile("s_waitcnt vmcnt(6)" ::: "memory"); // stage 15 landed
    else
      asm volatile("s_waitcnt vmcnt(10)" ::: "memory"); // stage h landed
    __builtin_amdgcn_s_barrier();
    asm volatile("" ::: "memory");
    __builtin_amdgcn_s_setprio(1);
    COMPUTE1(KS + cb * 4096, a0c, a1c, lavc);
    __builtin_amdgcn_s_setprio(0);
    if (h + 1 < NH) {
      a0c = a0n; a1c = a1n; lavc = lavn;
    }
    cb = (cb + 1) & 3;
  }
#undef STAGE1
#undef LOADQ1
#undef COMPUTE1

  const float mx = fmaxf(mx01, mx23);
  if (__any(mx >= L01)) { // cold: recompute everything with direct loads
    float amask[4][4] = {};
#pragma unroll 1
    for (int h = 0; h < NH; ++h) {
      const _Float16* Kp =
          K + (size_t)(b * NH + h) * hstep + (size_t)k0 * DK;
      const size_t ho = (size_t)h * hstep;
      const f16x8 aq0 = *(const f16x8*)&Q[qbase + ho + quad * 8];
      const f16x8 aq1 = *(const f16x8*)&Q[qbase + ho + 32 + quad * 8];
      const float4 l4 = *(const float4*)&la[dbase + (size_t)h * SDIM];
      const float lar[4] = {l4.x, l4.y, l4.z, l4.w};
#pragma unroll 1
      for (int c = 0; c < 4; ++c) {
        const f16x8 b0 = *(const f16x8*)&Kp[(c * 16 + lr) * DK + quad * 8];
        const f16x8 b1 = *(const f16x8*)&Kp[(c * 16 + lr) * DK + 32 + quad * 8];
        f32x4 acc = {0.f, 0.f, 0.f, 0.f};
        acc = __builtin_amdgcn_mfma_f32_16x16x32_f16(aq0, b0, acc, 0, 0, 0);
        acc = __builtin_amdgcn_mfma_f32_16x16x32_f16(aq1, b1, acc, 0, 0, 0);
#pragma unroll 1
        for (int r = 0; r < 4; ++r) {
          const float p = __builtin_amdgcn_exp2f(acc[r] + lar[r]);
          if (p >= 0.1f) {
            amask[c][r] += 1.0f;
            int idx = atomicAdd(ecnt, 1);
            if (idx < MAXEV)
              ev[idx] = make_float4(
                  __int_as_float(b * NH + h),
                  __int_as_float(q0 + wave * 16 + quad * 4 + r),
                  __int_as_float(k0 + c * 16 + lr), p);
          }
        }
      }
    }
    // sparse attMask writes: only the nonzero entries (rest are memset 0)
#pragma unroll
    for (int c = 0; c < 4; ++c)
#pragma unroll
      for (int r = 0; r < 4; ++r)
        if (amask[c][r] != 0.0f) {
          const size_t row = (size_t)(b * SDIM) + q0 + wave * 16 + quad * 4 + r;
          attMask[row * SDIM + k0 + c * 16 + lr] = amask[c][r];
        }
  }
  // epilogue (attSum only): LDS transpose -> full-128B-line nt stores.
  const int g8 = t >> 3;       // 0..31: row within a 32-row half
  const int l8 = (t & 7) * 4;  // float col within the 128B line
  __syncthreads(); // all waves done with K-buffer LDS reads; KS -> Tbuf
#pragma unroll
  for (int c = 0; c < 4; ++c)
#pragma unroll
    for (int r = 0; r < 4; ++r)
      Tbuf[(wave * 16 + quad * 4 + r) * 68 + c * 16 + lr] = asum[c][r];
  __syncthreads();
#pragma unroll
  for (int p = 0; p < 2; ++p)
#pragma unroll
    for (int qh = 0; qh < 2; ++qh) {
      const int row = p * 32 + g8, col = qh * 32 + l8;
      f32x4 v = *(const f32x4*)&Tbuf[row * 68 + col];
      __builtin_nontemporal_store(
          v, (f32x4*)&attSum[((size_t)(b * SDIM) + q0 + row) * SDIM + k0 + col]);
    }
}

// ---------- K3b: apply rare events to merged ctx ----------
__global__ __launch_bounds__(64) void apply_events(
    const float4* __restrict__ ev, const int* __restrict__ ecnt,
    const float* __restrict__ V, float* __restrict__ merged,
    int* __restrict__ flags) {
  int n = *ecnt;
  if (n > MAXEV) n = MAXEV;
  const int d = threadIdx.x;
  for (int e = blockIdx.x; e < n; e += gridDim.x) {
    float4 r = ev[e];
    int bh = __float_as_int(r.x);
    int q = __float_as_int(r.y);
    int kc = __float_as_int(r.z);
    float p = r.w;
    int b = bh >> 4, h = bh & 15;
    atomicAdd(&merged[((size_t)(b * SDIM + q)) * DDIM + h * DK + d],
              p * V[((size_t)bh * SDIM + kc) * DK + d]);
    if (d == 0) flags[b * SDIM + q] = 1;
  }
}

// ---------- K4: output projection with all-zero-row-tile skip ----------
__global__ __launch_bounds__(256) void out_gemm(const float* __restrict__ A,
                                                const float* __restrict__ W,
                                                const float* __restrict__ bias,
                                                float* __restrict__ out,
                                                const int* __restrict__ flags) {
  __shared__ float As[16][68];
  __shared__ float Ws[16][68];
  __shared__ int anyF;
  const int t = threadIdx.x;
  const int tx = t & 15, ty = t >> 4;
  const int m0 = blockIdx.y * 64;
  const int n0 = blockIdx.x * 64;
  if (t == 0) anyF = 0;
  __syncthreads();
  if (t < 64 && flags[m0 + t]) anyF = 1;
  __syncthreads();
  const int nb = n0 + tx * 4;
  const float4 bv = *(const float4*)&bias[nb];
  if (!anyF) {
#pragma unroll
    for (int r = 0; r < 4; ++r)
      *(float4*)&out[(size_t)(m0 + ty * 4 + r) * DDIM + nb] = bv;
    return;
  }
  const int lr = t >> 2;
  const int lc = (t & 3) * 4;
  float acc[4][4] = {};
  for (int k0 = 0; k0 < DDIM; k0 += 16) {
    __syncthreads();
    float4 av = *(const float4*)&A[(size_t)(m0 + lr) * DDIM + k0 + lc];
    float4 wv = *(const float4*)&W[(size_t)(n0 + lr) * DDIM + k0 + lc];
    As[lc + 0][lr] = av.x; As[lc + 1][lr] = av.y;
    As[lc + 2][lr] = av.z; As[lc + 3][lr] = av.w;
    Ws[lc + 0][lr] = wv.x; Ws[lc + 1][lr] = wv.y;
    Ws[lc + 2][lr] = wv.z; Ws[lc + 3][lr] = wv.w;
    __syncthreads();
#pragma unroll
    for (int kk = 0; kk < 16; ++kk) {
      float4 a4 = *(const float4*)&As[kk][ty * 4];
      float4 b4 = *(const float4*)&Ws[kk][tx * 4];
      const float a[4] = {a4.x, a4.y, a4.z, a4.w};
      const float b[4] = {b4.x, b4.y, b4.z, b4.w};
#pragma unroll
      for (int r = 0; r < 4; ++r)
#pragma unroll
        for (int c = 0; c < 4; ++c)
          acc[r][c] = fmaf(a[r], b[c], acc[r][c]);
    }
  }
#pragma unroll
  for (int r = 0; r < 4; ++r) {
    float4 o;
    o.x = acc[r][0] + bv.x;
    o.y = acc[r][1] + bv.y;
    o.z = acc[r][2] + bv.z;
    o.w = acc[r][3] + bv.w;
    *(float4*)&out[(size_t)(m0 + ty * 4 + r) * DDIM + nb] = o;
  }
}

// ---------- launcher ----------
extern "C" void kernel_launch(void* const* d_in, const int* in_sizes, int n_in,
                              void* d_out, int out_size, void* d_ws,
                              size_t ws_size, hipStream_t stream) {
  const float* x = (const float*)d_in[0];
  const float* Wq = (const float*)d_in[1];
  const float* bq = (const float*)d_in[2];
  const float* Wk = (const float*)d_in[3];
  const float* bk = (const float*)d_in[4];
  const float* Wv = (const float*)d_in[5];
  const float* bv = (const float*)d_in[6];
  const float* Wo = (const float*)d_in[7];
  const float* bo = (const float*)d_in[8];

  float* out = (float*)d_out;
  float* attSum = out + (size_t)MROWS * DDIM;
  float* attMask = attSum + (size_t)NB * SDIM * SDIM;

  char* ws = (char*)d_ws;
  const size_t bigF = (size_t)MROWS * DDIM * sizeof(float);    // 16.78 MB
  const size_t bigH = (size_t)MROWS * DDIM * sizeof(_Float16); // 8.39 MB
  const size_t wH = (size_t)DDIM * DDIM * sizeof(_Float16);    // 2.10 MB
  // zero-init region first (merged+flags+ecnt contiguous -> ONE memset)
  float* merged = (float*)ws;    ws += bigF;
  int* flags = (int*)ws;         ws += (size_t)MROWS * sizeof(int);
  int* ecnt = (int*)ws;          ws += 16;
  const size_t zeroSpan = bigF + (size_t)MROWS * sizeof(int) + 16;
  _Float16* Qh = (_Float16*)ws;  ws += bigH;
  _Float16* Kh = (_Float16*)ws;  ws += bigH;
  float* V = (float*)ws;         ws += bigF;
  _Float16* xh = (_Float16*)ws;  ws += bigH;
  _Float16* Wqh = (_Float16*)ws; ws += wH;
  _Float16* Wkh = (_Float16*)ws; ws += wH;
  _Float16* Wvh = (_Float16*)ws; ws += wH;
  float* laBuf = (float*)ws;     ws += (size_t)NB * NH * SDIM * sizeof(float);
  float4* ev = (float4*)ws;      ws += (size_t)MAXEV * sizeof(float4);

  hipMemsetAsync(merged, 0, zeroSpan, stream); // merged + flags + ecnt
  // attMask is written sparsely by attn_pass2's cold path only
  hipMemsetAsync(attMask, 0, (size_t)NB * SDIM * SDIM * sizeof(float), stream);

  dim3 blk(256);
  cvt_f16<<<dim3(7168), blk, 0, stream>>>(x, Wq, Wk, Wv, xh, Wqh, Wkh, Wvh);
  proj_gemm<<<dim3(8, 32, 3), blk, 0, stream>>>(xh, Wqh, Wkh, Wvh, bq, bk, bv,
                                                Qh, Kh, V);
  attn_denom<<<dim3(1024), blk, 0, stream>>>(Qh, Kh, laBuf);
  attn_pass2<<<dim3(2048), blk, 0, stream>>>(Qh, Kh, laBuf, attSum,
                                             attMask, ev, ecnt);
  apply_events<<<dim3(256), dim3(64), 0, stream>>>(ev, ecnt, V, merged, flags);
  out_gemm<<<dim3(16, 64), blk, 0, stream>>>(merged, Wo, bo, out, flags);
}

// Round 16
// 244.851 us; speedup vs baseline: 1.0110x; 1.0110x over previous
//
#include <hip/hip_runtime.h>

#define SDIM 2048
#define DDIM 1024
#define NH 16
#define DK 64
#define NB 2
#define MROWS (NB * SDIM) // 4096
#define MAXEV 65536
#define EXPC 0.18033688011112f // 0.125 * log2(e), folded into Q at projection
#define L01 -3.3219281f        // log2(0.1)

typedef _Float16 f16x8 __attribute__((ext_vector_type(8)));
typedef _Float16 f16x4 __attribute__((ext_vector_type(4)));
typedef float f32x4 __attribute__((ext_vector_type(4)));

__device__ __forceinline__ void ld_lds16(const _Float16* g, _Float16* l) {
  __builtin_amdgcn_global_load_lds(
      (const __attribute__((address_space(1))) void*)g,
      (__attribute__((address_space(3))) void*)l, 16, 0, 0);
}

// ---------- K0: fp32 -> fp16 convert, all four arrays in one launch ----------
__global__ __launch_bounds__(256) void cvt_f16(
    const float* __restrict__ x, const float* __restrict__ wq,
    const float* __restrict__ wk, const float* __restrict__ wv,
    _Float16* __restrict__ xh, _Float16* __restrict__ wqh,
    _Float16* __restrict__ wkh, _Float16* __restrict__ wvh) {
  int i = blockIdx.x * 256 + threadIdx.x; // float4 index
  const float* src;
  _Float16* dst;
  int off;
  if (i < 1048576) {
    src = x; dst = xh; off = i;
  } else if (i < 1310720) {
    src = wq; dst = wqh; off = i - 1048576;
  } else if (i < 1572864) {
    src = wk; dst = wkh; off = i - 1310720;
  } else {
    src = wv; dst = wvh; off = i - 1572864;
  }
  float4 v = ((const float4*)src)[off];
  f16x4 h;
  h[0] = (_Float16)v.x; h[1] = (_Float16)v.y;
  h[2] = (_Float16)v.z; h[3] = (_Float16)v.w;
  ((f16x4*)dst)[off] = h;
}

// ---------- K1: fused QKV projection, fp16 MFMA, 128x128 tile, BK=64.
// r10 form (the 243us-best config): single-buffer 16KB sA/sB, two
// __syncthreads per K-step. Q output pre-scaled by EXPC. ----------
__global__ __launch_bounds__(256, 2) void proj_gemm(
    const _Float16* __restrict__ xh, const _Float16* __restrict__ Wqh,
    const _Float16* __restrict__ Wkh, const _Float16* __restrict__ Wvh,
    const float* __restrict__ bq, const float* __restrict__ bk,
    const float* __restrict__ bv, _Float16* __restrict__ Qo,
    _Float16* __restrict__ Ko, float* __restrict__ Vo) {
  __shared__ _Float16 sA[128 * 64]; // 16KB, XOR-swizzled chunks
  __shared__ _Float16 sB[128 * 64];
  const int t = threadIdx.x;
  const int lane = t & 63, wv = t >> 6;
  const int lr = lane & 15, quad = lane >> 4;
  const int wm = wv >> 1, wn = wv & 1;
  const int m0 = blockIdx.y * 128, n0 = blockIdx.x * 128;
  const int z = blockIdx.z;
  const _Float16* Bp = z == 0 ? Wqh : (z == 1 ? Wkh : Wvh);
  const float* bias = z == 0 ? bq : (z == 1 ? bk : bv);

  const int strow = t >> 3;            // 0..31 per issue
  const int stchunk = t & 7;           // phys chunk
  const int stsrc = (stchunk ^ (strow & 7)) * 8; // src col (halfs)

  f32x4 acc[4][4];
#pragma unroll
  for (int i = 0; i < 4; ++i)
#pragma unroll
    for (int j = 0; j < 4; ++j) acc[i][j] = (f32x4){0.f, 0.f, 0.f, 0.f};

  for (int k0 = 0; k0 < DDIM; k0 += 64) {
    __syncthreads(); // prior LDS reads complete
#pragma unroll
    for (int i = 0; i < 4; ++i) {
      const int row = i * 32 + strow;
      ld_lds16(&xh[(size_t)(m0 + row) * DDIM + k0 + stsrc],
               &sA[row * 64 + stchunk * 8]);
      ld_lds16(&Bp[(size_t)(n0 + row) * DDIM + k0 + stsrc],
               &sB[row * 64 + stchunk * 8]);
    }
    __syncthreads(); // drains vmcnt: LDS visible
    f16x8 af[4][2], bf[4][2];
#pragma unroll
    for (int i = 0; i < 4; ++i)
#pragma unroll
      for (int kk = 0; kk < 2; ++kk) {
        const int ph = ((kk * 4 + quad) ^ (lr & 7)) * 8;
        af[i][kk] = *(const f16x8*)&sA[(wm * 64 + i * 16 + lr) * 64 + ph];
        bf[i][kk] = *(const f16x8*)&sB[(wn * 64 + i * 16 + lr) * 64 + ph];
      }
#pragma unroll
    for (int kk = 0; kk < 2; ++kk)
#pragma unroll
      for (int i = 0; i < 4; ++i)
#pragma unroll
        for (int j = 0; j < 4; ++j)
          acc[i][j] = __builtin_amdgcn_mfma_f32_16x16x32_f16(
              af[i][kk], bf[j][kk], acc[i][j], 0, 0, 0);
  }
  // epilogue: bias + head-split store (C layout: col=lane&15, row=quad*4+r)
#pragma unroll
  for (int j = 0; j < 4; ++j) {
    const int ng = n0 + wn * 64 + j * 16 + lr;
    const float bvv = bias[ng];
    const int h = ng >> 6, d = ng & 63;
#pragma unroll
    for (int i = 0; i < 4; ++i) {
#pragma unroll
      for (int r = 0; r < 4; ++r) {
        const int mg = m0 + wm * 64 + i * 16 + quad * 4 + r;
        const int b = mg >> 11, s = mg & 2047;
        const float o = acc[i][j][r] + bvv;
        const size_t off = ((size_t)(b * NH + h) * SDIM + s) * DK + d;
        if (z == 0)
          Qo[off] = (_Float16)(o * EXPC); // pre-scaled Q
        else if (z == 1)
          Ko[off] = (_Float16)o;
        else
          Vo[off] = o;
      }
    }
  }
}

// ---------- K2: la = -log2(sum_k 2^(Q'.K)) per row. r10 form (243us-best):
// triple buffer, raw s_barrier + counted vmcnt, 128 K-rows/stage, loop-
// carried K pointer, setprio compute cluster. ----------
__global__ __launch_bounds__(256, 3) void attn_denom(
    const _Float16* __restrict__ Q, const _Float16* __restrict__ K,
    float* __restrict__ laOut) {
  __shared__ __align__(16) _Float16 KS[3 * 8192]; // 48KB: 3 x 128x64 K tiles
  const int t = threadIdx.x;
  const int lane = t & 63, wave = t >> 6;
  const int quad = lane >> 4, lr = lane & 15;
  const int id = blockIdx.x;
  const int xcd = id & 7, inner = id >> 3; // inner in [0,128)
  const int bh = xcd * 4 + (inner >> 5);
  const int q0 = (inner & 31) * 64;
  const _Float16* Qh = Q + (size_t)bh * SDIM * DK;
  const _Float16* Kh = K + (size_t)bh * SDIM * DK;
  const size_t qoff = (size_t)(q0 + wave * 16 + lr) * DK + quad * 8;
  const f16x8 aq0 = *(const f16x8*)&Qh[qoff];
  const f16x8 aq1 = *(const f16x8*)&Qh[qoff + 32];
  const int strow = t >> 3, stchunk = t & 7;
  const int stsrc = (stchunk ^ (strow & 7)) * 8;
  const int ph0 = (quad ^ (lr & 7)) * 8;
  const int ph1 = ((4 + quad) ^ (lr & 7)) * 8;

#define STAGE_DN(KP, BUF)                                                  \
  {                                                                        \
    _Pragma("unroll") for (int i = 0; i < 4; ++i)                          \
        ld_lds16(&(KP)[(size_t)(i * 32 + strow) * DK + stsrc],             \
                 &(BUF)[(i * 32 + strow) * 64 + stchunk * 8]);             \
  }

#define COMPUTE_DN(BUF)                                                   \
  _Pragma("unroll") for (int c = 0; c < 8; ++c) {                         \
    f16x8 b0 = *(const f16x8*)&(BUF)[(c * 16 + lr) * 64 + ph0];           \
    f16x8 b1 = *(const f16x8*)&(BUF)[(c * 16 + lr) * 64 + ph1];           \
    f32x4 acc = {0.f, 0.f, 0.f, 0.f};                                     \
    acc = __builtin_amdgcn_mfma_f32_16x16x32_f16(aq0, b0, acc, 0, 0, 0);  \
    acc = __builtin_amdgcn_mfma_f32_16x16x32_f16(aq1, b1, acc, 0, 0, 0);  \
    _Pragma("unroll") for (int r = 0; r < 4; ++r)                         \
        dsum[r] += __builtin_amdgcn_exp2f(acc[r]);                        \
  }

  float dsum[4] = {0.f, 0.f, 0.f, 0.f};
  const _Float16* kp = Kh; // loop-carried stage pointer
  STAGE_DN(kp, KS);
  kp += 128 * DK;
  int cb = 0;
#pragma unroll 1
  for (int kt = 0; kt < 16; ++kt) {
    const int nb_ = cb == 2 ? 0 : cb + 1;
    if (kt + 1 < 16) {
      STAGE_DN(kp, KS + nb_ * 8192);
      kp += 128 * DK;
    }
    asm volatile("" ::: "memory");
    if (kt + 1 < 16)
      asm volatile("s_waitcnt vmcnt(4)" ::: "memory"); // stage kt landed
    else
      asm volatile("s_waitcnt vmcnt(0)" ::: "memory");
    __builtin_amdgcn_s_barrier();
    asm volatile("" ::: "memory");
    __builtin_amdgcn_s_setprio(1);
    COMPUTE_DN(KS + cb * 8192);
    __builtin_amdgcn_s_setprio(0);
    cb = nb_;
  }
#pragma unroll
  for (int m = 1; m < 16; m <<= 1)
#pragma unroll
    for (int r = 0; r < 4; ++r)
      dsum[r] += __shfl_xor(dsum[r], m, 64);
  if (lr == 0) {
#pragma unroll
    for (int r = 0; r < 4; ++r)
      laOut[(size_t)bh * SDIM + q0 + wave * 16 + quad * 4 + r] =
          -__builtin_amdgcn_logf(dsum[r]); // -log2(dsum)
  }
#undef STAGE_DN
#undef COMPUTE_DN
}

// ---------- K3: att_sum dense. r10 form (243us-best): triple buffer, raw
// s_barrier + counted vmcnt(10), 2 heads/stage, la in MFMA C operand, max3
// chains, pointer bumps, setprio. K L2-resident via XCD swizzle
// (FETCH=16.7MB verified); attMask sparse (cold path, pre-memset); attSum
// epilogue: LDS transpose -> full-128B-line nt stores (WRITE=32.8MB). ----------
__global__ __launch_bounds__(256, 3) void attn_pass2(
    const _Float16* __restrict__ Q, const _Float16* __restrict__ K,
    const float* __restrict__ la, float* __restrict__ attSum,
    float* __restrict__ attMask, float4* __restrict__ ev,
    int* __restrict__ ecnt) {
  __shared__ __align__(16) _Float16 KS[3 * 8192]; // 48KB: 3 x 2-head tiles
  float* Tbuf = (float*)KS;                       // epilogue alias (17.4KB)
  const int t = threadIdx.x;
  const int lane = t & 63, wave = t >> 6;
  const int quad = lane >> 4, lr = lane & 15;
  // XCD swizzle: 2048 blocks, id%8 = XCD. Each XCD: one batch half-quadrant
  // (16 q0-tiles x 16 k0-tiles), k0 fastest within.
  const int id = blockIdx.x;
  const int xcd = id & 7, inner = id >> 3; // inner in [0,256)
  const int b = xcd >> 2;
  const int q0 = (((xcd >> 1) & 1) * 16 + (inner >> 4)) * 64;
  const int k0 = ((xcd & 1) * 16 + (inner & 15)) * 64;
  const int strow = t >> 3, stchunk = t & 7;
  const int stsrc = (stchunk ^ (strow & 7)) * 8;
  const int ph0 = (quad ^ (lr & 7)) * 8;
  const int ph1 = ((4 + quad) ^ (lr & 7)) * 8;

  const size_t qbase = ((size_t)(b * NH) * SDIM + q0 + wave * 16 + lr) * DK;
  const size_t dbase = (size_t)(b * NH) * SDIM + q0 + wave * 16 + quad * 4;
  const size_t hstep = (size_t)SDIM * DK;

  float asum[4][4] = {};
  float mx01 = -1e30f, mx23 = -1e30f; // 2 fused max chains

  f16x8 a0c[2], a1c[2], a0n[2], a1n[2];
  float4 lavc[2], lavn[2];

#define STAGE2(KP, BUF)                                                      \
  {                                                                          \
    _Pragma("unroll") for (int hh = 0; hh < 2; ++hh) {                       \
      const _Float16* Kpp = (KP) + (size_t)hh * hstep;                       \
      _Pragma("unroll") for (int i = 0; i < 2; ++i)                          \
          ld_lds16(&Kpp[(size_t)(i * 32 + strow) * DK + stsrc],              \
                   &(BUF)[hh * 4096 + (i * 32 + strow) * 64 + stchunk * 8]); \
    }                                                                        \
  }

#define LOADQ2(QP, LAP, A0, A1, LV)                                          \
  {                                                                          \
    _Pragma("unroll") for (int hh = 0; hh < 2; ++hh) {                       \
      const _Float16* qpp = (QP) + (size_t)hh * hstep;                       \
      A0[hh] = *(const f16x8*)&qpp[quad * 8];                                \
      A1[hh] = *(const f16x8*)&qpp[32 + quad * 8];                           \
      LV[hh] = *(const float4*)&(LAP)[(size_t)hh * SDIM];                    \
    }                                                                        \
  }

#define COMPUTE2(BUF, A0, A1, LV)                                            \
  _Pragma("unroll") for (int hh = 0; hh < 2; ++hh) {                         \
    const _Float16* Ksh = &(BUF)[hh * 4096];                                 \
    const f32x4 cinit = {LV[hh].x, LV[hh].y, LV[hh].z, LV[hh].w};            \
    _Pragma("unroll") for (int c = 0; c < 4; ++c) {                          \
      f16x8 b0 = *(const f16x8*)&Ksh[(c * 16 + lr) * 64 + ph0];              \
      f16x8 b1 = *(const f16x8*)&Ksh[(c * 16 + lr) * 64 + ph1];              \
      f32x4 acc = cinit; /* la folded into MFMA C operand */                 \
      acc = __builtin_amdgcn_mfma_f32_16x16x32_f16(A0[hh], b0, acc, 0, 0, 0);\
      acc = __builtin_amdgcn_mfma_f32_16x16x32_f16(A1[hh], b1, acc, 0, 0, 0);\
      mx01 = fmaxf(fmaxf(acc[0], acc[1]), mx01); /* v_max3 */                \
      mx23 = fmaxf(fmaxf(acc[2], acc[3]), mx23);                             \
      asum[c][0] += __builtin_amdgcn_exp2f(acc[0]);                          \
      asum[c][1] += __builtin_amdgcn_exp2f(acc[1]);                          \
      asum[c][2] += __builtin_amdgcn_exp2f(acc[2]);                          \
      asum[c][3] += __builtin_amdgcn_exp2f(acc[3]);                          \
    }                                                                        \
  }

  const _Float16* kp = K + (size_t)(b * NH) * hstep + (size_t)k0 * DK;
  const _Float16* qp = Q + qbase;
  const float* lap = la + dbase;
  STAGE2(kp, KS);
  LOADQ2(qp, lap, a0c, a1c, lavc);
  kp += 2 * hstep; qp += 2 * hstep; lap += 2 * SDIM;
  int cb = 0;
#pragma unroll 1
  for (int s = 0; s < 8; ++s) {
    const int nb_ = cb == 2 ? 0 : cb + 1;
    if (s + 1 < 8) {
      STAGE2(kp, KS + nb_ * 8192);
      LOADQ2(qp, lap, a0n, a1n, lavn);
      kp += 2 * hstep; qp += 2 * hstep; lap += 2 * SDIM;
    }
    asm volatile("" ::: "memory");
    if (s + 1 < 8)
      asm volatile("s_waitcnt vmcnt(10)" ::: "memory"); // stage s landed
    else
      asm volatile("s_waitcnt vmcnt(0)" ::: "memory");
    __builtin_amdgcn_s_barrier();
    asm volatile("" ::: "memory");
    __builtin_amdgcn_s_setprio(1);
    COMPUTE2(KS + cb * 8192, a0c, a1c, lavc);
    __builtin_amdgcn_s_setprio(0);
    if (s + 1 < 8) {
#pragma unroll
      for (int hh = 0; hh < 2; ++hh) {
        a0c[hh] = a0n[hh]; a1c[hh] = a1n[hh]; lavc[hh] = lavn[hh];
      }
    }
    cb = nb_;
  }
#undef STAGE2
#undef LOADQ2
#undef COMPUTE2

  const float mx = fmaxf(mx01, mx23);
  if (__any(mx >= L01)) { // cold: recompute everything with direct loads
    float amask[4][4] = {};
#pragma unroll 1
    for (int h = 0; h < NH; ++h) {
      const _Float16* Kp =
          K + (size_t)(b * NH + h) * hstep + (size_t)k0 * DK;
      const size_t ho = (size_t)h * hstep;
      const f16x8 aq0 = *(const f16x8*)&Q[qbase + ho + quad * 8];
      const f16x8 aq1 = *(const f16x8*)&Q[qbase + ho + 32 + quad * 8];
      const float4 l4 = *(const float4*)&la[dbase + (size_t)h * SDIM];
      const float lar[4] = {l4.x, l4.y, l4.z, l4.w};
#pragma unroll 1
      for (int c = 0; c < 4; ++c) {
        const f16x8 b0 = *(const f16x8*)&Kp[(c * 16 + lr) * DK + quad * 8];
        const f16x8 b1 = *(const f16x8*)&Kp[(c * 16 + lr) * DK + 32 + quad * 8];
        f32x4 acc = {0.f, 0.f, 0.f, 0.f};
        acc = __builtin_amdgcn_mfma_f32_16x16x32_f16(aq0, b0, acc, 0, 0, 0);
        acc = __builtin_amdgcn_mfma_f32_16x16x32_f16(aq1, b1, acc, 0, 0, 0);
#pragma unroll 1
        for (int r = 0; r < 4; ++r) {
          const float p = __builtin_amdgcn_exp2f(acc[r] + lar[r]);
          if (p >= 0.1f) {
            amask[c][r] += 1.0f;
            int idx = atomicAdd(ecnt, 1);
            if (idx < MAXEV)
              ev[idx] = make_float4(
                  __int_as_float(b * NH + h),
                  __int_as_float(q0 + wave * 16 + quad * 4 + r),
                  __int_as_float(k0 + c * 16 + lr), p);
          }
        }
      }
    }
    // sparse attMask writes: only the nonzero entries (rest are memset 0)
#pragma unroll
    for (int c = 0; c < 4; ++c)
#pragma unroll
      for (int r = 0; r < 4; ++r)
        if (amask[c][r] != 0.0f) {
          const size_t row = (size_t)(b * SDIM) + q0 + wave * 16 + quad * 4 + r;
          attMask[row * SDIM + k0 + c * 16 + lr] = amask[c][r];
        }
  }
  // epilogue (attSum only): LDS transpose -> full-128B-line nt stores.
  const int g8 = t >> 3;       // 0..31: row within a 32-row half
  const int l8 = (t & 7) * 4;  // float col within the 128B line
  __syncthreads(); // all waves done with K-buffer LDS reads; KS -> Tbuf
#pragma unroll
  for (int c = 0; c < 4; ++c)
#pragma unroll
    for (int r = 0; r < 4; ++r)
      Tbuf[(wave * 16 + quad * 4 + r) * 68 + c * 16 + lr] = asum[c][r];
  __syncthreads();
#pragma unroll
  for (int p = 0; p < 2; ++p)
#pragma unroll
    for (int qh = 0; qh < 2; ++qh) {
      const int row = p * 32 + g8, col = qh * 32 + l8;
      f32x4 v = *(const f32x4*)&Tbuf[row * 68 + col];
      __builtin_nontemporal_store(
          v, (f32x4*)&attSum[((size_t)(b * SDIM) + q0 + row) * SDIM + k0 + col]);
    }
}

// ---------- K3b: apply rare events to merged ctx ----------
__global__ __launch_bounds__(64) void apply_events(
    const float4* __restrict__ ev, const int* __restrict__ ecnt,
    const float* __restrict__ V, float* __restrict__ merged,
    int* __restrict__ flags) {
  int n = *ecnt;
  if (n > MAXEV) n = MAXEV;
  const int d = threadIdx.x;
  for (int e = blockIdx.x; e < n; e += gridDim.x) {
    float4 r = ev[e];
    int bh = __float_as_int(r.x);
    int q = __float_as_int(r.y);
    int kc = __float_as_int(r.z);
    float p = r.w;
    int b = bh >> 4, h = bh & 15;
    atomicAdd(&merged[((size_t)(b * SDIM + q)) * DDIM + h * DK + d],
              p * V[((size_t)bh * SDIM + kc) * DK + d]);
    if (d == 0) flags[b * SDIM + q] = 1;
  }
}

// ---------- K4: output projection with all-zero-row-tile skip ----------
__global__ __launch_bounds__(256) void out_gemm(const float* __restrict__ A,
                                                const float* __restrict__ W,
                                                const float* __restrict__ bias,
                                                float* __restrict__ out,
                                                const int* __restrict__ flags) {
  __shared__ float As[16][68];
  __shared__ float Ws[16][68];
  __shared__ int anyF;
  const int t = threadIdx.x;
  const int tx = t & 15, ty = t >> 4;
  const int m0 = blockIdx.y * 64;
  const int n0 = blockIdx.x * 64;
  if (t == 0) anyF = 0;
  __syncthreads();
  if (t < 64 && flags[m0 + t]) anyF = 1;
  __syncthreads();
  const int nb = n0 + tx * 4;
  const float4 bv = *(const float4*)&bias[nb];
  if (!anyF) {
#pragma unroll
    for (int r = 0; r < 4; ++r)
      *(float4*)&out[(size_t)(m0 + ty * 4 + r) * DDIM + nb] = bv;
    return;
  }
  const int lr = t >> 2;
  const int lc = (t & 3) * 4;
  float acc[4][4] = {};
  for (int k0 = 0; k0 < DDIM; k0 += 16) {
    __syncthreads();
    float4 av = *(const float4*)&A[(size_t)(m0 + lr) * DDIM + k0 + lc];
    float4 wv = *(const float4*)&W[(size_t)(n0 + lr) * DDIM + k0 + lc];
    As[lc + 0][lr] = av.x; As[lc + 1][lr] = av.y;
    As[lc + 2][lr] = av.z; As[lc + 3][lr] = av.w;
    Ws[lc + 0][lr] = wv.x; Ws[lc + 1][lr] = wv.y;
    Ws[lc + 2][lr] = wv.z; Ws[lc + 3][lr] = wv.w;
    __syncthreads();
#pragma unroll
    for (int kk = 0; kk < 16; ++kk) {
      float4 a4 = *(const float4*)&As[kk][ty * 4];
      float4 b4 = *(const float4*)&Ws[kk][tx * 4];
      const float a[4] = {a4.x, a4.y, a4.z, a4.w};
      const float b[4] = {b4.x, b4.y, b4.z, b4.w};
#pragma unroll
      for (int r = 0; r < 4; ++r)
#pragma unroll
        for (int c = 0; c < 4; ++c)
          acc[r][c] = fmaf(a[r], b[c], acc[r][c]);
    }
  }
#pragma unroll
  for (int r = 0; r < 4; ++r) {
    float4 o;
    o.x = acc[r][0] + bv.x;
    o.y = acc[r][1] + bv.y;
    o.z = acc[r][2] + bv.z;
    o.w = acc[r][3] + bv.w;
    *(float4*)&out[(size_t)(m0 + ty * 4 + r) * DDIM + nb] = o;
  }
}

// ---------- launcher ----------
extern "C" void kernel_launch(void* const* d_in, const int* in_sizes, int n_in,
                              void* d_out, int out_size, void* d_ws,
                              size_t ws_size, hipStream_t stream) {
  const float* x = (const float*)d_in[0];
  const float* Wq = (const float*)d_in[1];
  const float* bq = (const float*)d_in[2];
  const float* Wk = (const float*)d_in[3];
  const float* bk = (const float*)d_in[4];
  const float* Wv = (const float*)d_in[5];
  const float* bv = (const float*)d_in[6];
  const float* Wo = (const float*)d_in[7];
  const float* bo = (const float*)d_in[8];

  float* out = (float*)d_out;
  float* attSum = out + (size_t)MROWS * DDIM;
  float* attMask = attSum + (size_t)NB * SDIM * SDIM;

  char* ws = (char*)d_ws;
  const size_t bigF = (size_t)MROWS * DDIM * sizeof(float);    // 16.78 MB
  const size_t bigH = (size_t)MROWS * DDIM * sizeof(_Float16); // 8.39 MB
  const size_t wH = (size_t)DDIM * DDIM * sizeof(_Float16);    // 2.10 MB
  _Float16* Qh = (_Float16*)ws;  ws += bigH;
  _Float16* Kh = (_Float16*)ws;  ws += bigH;
  float* V = (float*)ws;         ws += bigF;
  float* merged = (float*)ws;    ws += bigF;
  _Float16* xh = (_Float16*)ws;  ws += bigH;
  _Float16* Wqh = (_Float16*)ws; ws += wH;
  _Float16* Wkh = (_Float16*)ws; ws += wH;
  _Float16* Wvh = (_Float16*)ws; ws += wH;
  float* laBuf = (float*)ws;     ws += (size_t)NB * NH * SDIM * sizeof(float);
  float4* ev = (float4*)ws;      ws += (size_t)MAXEV * sizeof(float4);
  int* flags = (int*)ws;         ws += (size_t)MROWS * sizeof(int);
  int* ecnt = (int*)ws;          ws += 16;

  hipMemsetAsync(merged, 0, bigF, stream);
  hipMemsetAsync(flags, 0, (size_t)MROWS * sizeof(int), stream);
  hipMemsetAsync(ecnt, 0, 16, stream);
  // attMask is written sparsely by attn_pass2's cold path only
  hipMemsetAsync(attMask, 0, (size_t)NB * SDIM * SDIM * sizeof(float), stream);

  dim3 blk(256);
  cvt_f16<<<dim3(7168), blk, 0, stream>>>(x, Wq, Wk, Wv, xh, Wqh, Wkh, Wvh);
  proj_gemm<<<dim3(8, 32, 3), blk, 0, stream>>>(xh, Wqh, Wkh, Wvh, bq, bk, bv,
                                                Qh, Kh, V);
  attn_denom<<<dim3(1024), blk, 0, stream>>>(Qh, Kh, laBuf);
  attn_pass2<<<dim3(2048), blk, 0, stream>>>(Qh, Kh, laBuf, attSum,
                                             attMask, ev, ecnt);
  apply_events<<<dim3(256), dim3(64), 0, stream>>>(ev, ecnt, V, merged, flags);
  out_gemm<<<dim3(16, 64), blk, 0, stream>>>(merged, Wo, bo, out, flags);
}

// Round 17
// 240.722 us; speedup vs baseline: 1.0284x; 1.0172x over previous
//
#include <hip/hip_runtime.h>

#define SDIM 2048
#define DDIM 1024
#define NH 16
#define DK 64
#define NB 2
#define MROWS (NB * SDIM) // 4096
#define MAXEV 65536
#define EXPC 0.18033688011112f // 0.125 * log2(e), folded into Q at projection
#define L01 -3.3219281f        // log2(0.1)

typedef _Float16 f16x8 __attribute__((ext_vector_type(8)));
typedef _Float16 f16x4 __attribute__((ext_vector_type(4)));
typedef float f32x4 __attribute__((ext_vector_type(4)));

__device__ __forceinline__ void ld_lds16(const _Float16* g, _Float16* l) {
  __builtin_amdgcn_global_load_lds(
      (const __attribute__((address_space(1))) void*)g,
      (__attribute__((address_space(3))) void*)l, 16, 0, 0);
}

// ---------- K0: fp32 -> fp16 convert, all four arrays in one launch ----------
__global__ __launch_bounds__(256) void cvt_f16(
    const float* __restrict__ x, const float* __restrict__ wq,
    const float* __restrict__ wk, const float* __restrict__ wv,
    _Float16* __restrict__ xh, _Float16* __restrict__ wqh,
    _Float16* __restrict__ wkh, _Float16* __restrict__ wvh) {
  int i = blockIdx.x * 256 + threadIdx.x; // float4 index
  const float* src;
  _Float16* dst;
  int off;
  if (i < 1048576) {
    src = x; dst = xh; off = i;
  } else if (i < 1310720) {
    src = wq; dst = wqh; off = i - 1048576;
  } else if (i < 1572864) {
    src = wk; dst = wkh; off = i - 1310720;
  } else {
    src = wv; dst = wvh; off = i - 1572864;
  }
  float4 v = ((const float4*)src)[off];
  f16x4 h;
  h[0] = (_Float16)v.x; h[1] = (_Float16)v.y;
  h[2] = (_Float16)v.z; h[3] = (_Float16)v.w;
  ((f16x4*)dst)[off] = h;
}

// ---------- K1: fused QKV projection, fp16 MFMA, 128x128 tile, BK=64.
// r10 form (the 243us-best config): single-buffer 16KB sA/sB, two
// __syncthreads per K-step. Q output pre-scaled by EXPC. ----------
__global__ __launch_bounds__(256, 2) void proj_gemm(
    const _Float16* __restrict__ xh, const _Float16* __restrict__ Wqh,
    const _Float16* __restrict__ Wkh, const _Float16* __restrict__ Wvh,
    const float* __restrict__ bq, const float* __restrict__ bk,
    const float* __restrict__ bv, _Float16* __restrict__ Qo,
    _Float16* __restrict__ Ko, float* __restrict__ Vo) {
  __shared__ _Float16 sA[128 * 64]; // 16KB, XOR-swizzled chunks
  __shared__ _Float16 sB[128 * 64];
  const int t = threadIdx.x;
  const int lane = t & 63, wv = t >> 6;
  const int lr = lane & 15, quad = lane >> 4;
  const int wm = wv >> 1, wn = wv & 1;
  const int m0 = blockIdx.y * 128, n0 = blockIdx.x * 128;
  const int z = blockIdx.z;
  const _Float16* Bp = z == 0 ? Wqh : (z == 1 ? Wkh : Wvh);
  const float* bias = z == 0 ? bq : (z == 1 ? bk : bv);

  const int strow = t >> 3;            // 0..31 per issue
  const int stchunk = t & 7;           // phys chunk
  const int stsrc = (stchunk ^ (strow & 7)) * 8; // src col (halfs)

  f32x4 acc[4][4];
#pragma unroll
  for (int i = 0; i < 4; ++i)
#pragma unroll
    for (int j = 0; j < 4; ++j) acc[i][j] = (f32x4){0.f, 0.f, 0.f, 0.f};

  for (int k0 = 0; k0 < DDIM; k0 += 64) {
    __syncthreads(); // prior LDS reads complete
#pragma unroll
    for (int i = 0; i < 4; ++i) {
      const int row = i * 32 + strow;
      ld_lds16(&xh[(size_t)(m0 + row) * DDIM + k0 + stsrc],
               &sA[row * 64 + stchunk * 8]);
      ld_lds16(&Bp[(size_t)(n0 + row) * DDIM + k0 + stsrc],
               &sB[row * 64 + stchunk * 8]);
    }
    __syncthreads(); // drains vmcnt: LDS visible
    f16x8 af[4][2], bf[4][2];
#pragma unroll
    for (int i = 0; i < 4; ++i)
#pragma unroll
      for (int kk = 0; kk < 2; ++kk) {
        const int ph = ((kk * 4 + quad) ^ (lr & 7)) * 8;
        af[i][kk] = *(const f16x8*)&sA[(wm * 64 + i * 16 + lr) * 64 + ph];
        bf[i][kk] = *(const f16x8*)&sB[(wn * 64 + i * 16 + lr) * 64 + ph];
      }
#pragma unroll
    for (int kk = 0; kk < 2; ++kk)
#pragma unroll
      for (int i = 0; i < 4; ++i)
#pragma unroll
        for (int j = 0; j < 4; ++j)
          acc[i][j] = __builtin_amdgcn_mfma_f32_16x16x32_f16(
              af[i][kk], bf[j][kk], acc[i][j], 0, 0, 0);
  }
  // epilogue: bias + head-split store (C layout: col=lane&15, row=quad*4+r)
#pragma unroll
  for (int j = 0; j < 4; ++j) {
    const int ng = n0 + wn * 64 + j * 16 + lr;
    const float bvv = bias[ng];
    const int h = ng >> 6, d = ng & 63;
#pragma unroll
    for (int i = 0; i < 4; ++i) {
#pragma unroll
      for (int r = 0; r < 4; ++r) {
        const int mg = m0 + wm * 64 + i * 16 + quad * 4 + r;
        const int b = mg >> 11, s = mg & 2047;
        const float o = acc[i][j][r] + bvv;
        const size_t off = ((size_t)(b * NH + h) * SDIM + s) * DK + d;
        if (z == 0)
          Qo[off] = (_Float16)(o * EXPC); // pre-scaled Q
        else if (z == 1)
          Ko[off] = (_Float16)o;
        else
          Vo[off] = o;
      }
    }
  }
}

// ---------- K2: la = -log2(sum_k 2^(Q'.K)) per row. r10 form (243us-best):
// triple buffer, raw s_barrier + counted vmcnt, 128 K-rows/stage, loop-
// carried K pointer, setprio compute cluster. ----------
__global__ __launch_bounds__(256, 3) void attn_denom(
    const _Float16* __restrict__ Q, const _Float16* __restrict__ K,
    float* __restrict__ laOut) {
  __shared__ __align__(16) _Float16 KS[3 * 8192]; // 48KB: 3 x 128x64 K tiles
  const int t = threadIdx.x;
  const int lane = t & 63, wave = t >> 6;
  const int quad = lane >> 4, lr = lane & 15;
  const int id = blockIdx.x;
  const int xcd = id & 7, inner = id >> 3; // inner in [0,128)
  const int bh = xcd * 4 + (inner >> 5);
  const int q0 = (inner & 31) * 64;
  const _Float16* Qh = Q + (size_t)bh * SDIM * DK;
  const _Float16* Kh = K + (size_t)bh * SDIM * DK;
  const size_t qoff = (size_t)(q0 + wave * 16 + lr) * DK + quad * 8;
  const f16x8 aq0 = *(const f16x8*)&Qh[qoff];
  const f16x8 aq1 = *(const f16x8*)&Qh[qoff + 32];
  const int strow = t >> 3, stchunk = t & 7;
  const int stsrc = (stchunk ^ (strow & 7)) * 8;
  const int ph0 = (quad ^ (lr & 7)) * 8;
  const int ph1 = ((4 + quad) ^ (lr & 7)) * 8;

#define STAGE_DN(KP, BUF)                                                  \
  {                                                                        \
    _Pragma("unroll") for (int i = 0; i < 4; ++i)                          \
        ld_lds16(&(KP)[(size_t)(i * 32 + strow) * DK + stsrc],             \
                 &(BUF)[(i * 32 + strow) * 64 + stchunk * 8]);             \
  }

#define COMPUTE_DN(BUF)                                                   \
  _Pragma("unroll") for (int c = 0; c < 8; ++c) {                         \
    f16x8 b0 = *(const f16x8*)&(BUF)[(c * 16 + lr) * 64 + ph0];           \
    f16x8 b1 = *(const f16x8*)&(BUF)[(c * 16 + lr) * 64 + ph1];           \
    f32x4 acc = {0.f, 0.f, 0.f, 0.f};                                     \
    acc = __builtin_amdgcn_mfma_f32_16x16x32_f16(aq0, b0, acc, 0, 0, 0);  \
    acc = __builtin_amdgcn_mfma_f32_16x16x32_f16(aq1, b1, acc, 0, 0, 0);  \
    _Pragma("unroll") for (int r = 0; r < 4; ++r)                         \
        dsum[r] += __builtin_amdgcn_exp2f(acc[r]);                        \
  }

  float dsum[4] = {0.f, 0.f, 0.f, 0.f};
  const _Float16* kp = Kh; // loop-carried stage pointer
  STAGE_DN(kp, KS);
  kp += 128 * DK;
  int cb = 0;
#pragma unroll 1
  for (int kt = 0; kt < 16; ++kt) {
    const int nb_ = cb == 2 ? 0 : cb + 1;
    if (kt + 1 < 16) {
      STAGE_DN(kp, KS + nb_ * 8192);
      kp += 128 * DK;
    }
    asm volatile("" ::: "memory");
    if (kt + 1 < 16)
      asm volatile("s_waitcnt vmcnt(4)" ::: "memory"); // stage kt landed
    else
      asm volatile("s_waitcnt vmcnt(0)" ::: "memory");
    __builtin_amdgcn_s_barrier();
    asm volatile("" ::: "memory");
    __builtin_amdgcn_s_setprio(1);
    COMPUTE_DN(KS + cb * 8192);
    __builtin_amdgcn_s_setprio(0);
    cb = nb_;
  }
#pragma unroll
  for (int m = 1; m < 16; m <<= 1)
#pragma unroll
    for (int r = 0; r < 4; ++r)
      dsum[r] += __shfl_xor(dsum[r], m, 64);
  if (lr == 0) {
#pragma unroll
    for (int r = 0; r < 4; ++r)
      laOut[(size_t)bh * SDIM + q0 + wave * 16 + quad * 4 + r] =
          -__builtin_amdgcn_logf(dsum[r]); // -log2(dsum)
  }
#undef STAGE_DN
#undef COMPUTE_DN
}

// ---------- K3: att_sum dense. r14 form (best-measured pass2, 51.5us):
// 4-buffer ring, 1-head stages, K-DMA issued 2 STAGES AHEAD (Q/la 1
// ahead); steady vmcnt(10), final vmcnt(6). 32KB LDS -> 4 blocks/CU.
// Diet: la in MFMA C operand, max3 chains, pointer bumps, setprio. K
// L2-resident via XCD swizzle (FETCH=16.7MB); attMask sparse (cold path,
// pre-memset); attSum epilogue: LDS transpose -> full-128B-line nt stores. ----------
__global__ __launch_bounds__(256, 4) void attn_pass2(
    const _Float16* __restrict__ Q, const _Float16* __restrict__ K,
    const float* __restrict__ la, float* __restrict__ attSum,
    float* __restrict__ attMask, float4* __restrict__ ev,
    int* __restrict__ ecnt) {
  __shared__ __align__(16) _Float16 KS[4 * 4096]; // 32KB: 4 x 1-head tiles
  float* Tbuf = (float*)KS;                       // epilogue alias (17.4KB)
  const int t = threadIdx.x;
  const int lane = t & 63, wave = t >> 6;
  const int quad = lane >> 4, lr = lane & 15;
  // XCD swizzle: 2048 blocks, id%8 = XCD. Each XCD: one batch half-quadrant
  // (16 q0-tiles x 16 k0-tiles), k0 fastest within.
  const int id = blockIdx.x;
  const int xcd = id & 7, inner = id >> 3; // inner in [0,256)
  const int b = xcd >> 2;
  const int q0 = (((xcd >> 1) & 1) * 16 + (inner >> 4)) * 64;
  const int k0 = ((xcd & 1) * 16 + (inner & 15)) * 64;
  const int strow = t >> 3, stchunk = t & 7;
  const int stsrc = (stchunk ^ (strow & 7)) * 8;
  const int ph0 = (quad ^ (lr & 7)) * 8;
  const int ph1 = ((4 + quad) ^ (lr & 7)) * 8;

  const size_t qbase = ((size_t)(b * NH) * SDIM + q0 + wave * 16 + lr) * DK;
  const size_t dbase = (size_t)(b * NH) * SDIM + q0 + wave * 16 + quad * 4;
  const size_t hstep = (size_t)SDIM * DK;

  float asum[4][4] = {};
  float mx01 = -1e30f, mx23 = -1e30f; // 2 fused max chains

  f16x8 a0c, a1c, a0n, a1n;
  float4 lavc, lavn;

#define STAGE1(KP, BUF)                                                      \
  {                                                                          \
    _Pragma("unroll") for (int i = 0; i < 2; ++i)                            \
        ld_lds16(&(KP)[(size_t)(i * 32 + strow) * DK + stsrc],               \
                 &(BUF)[(i * 32 + strow) * 64 + stchunk * 8]);               \
  }

#define LOADQ1(QP, LAP, A0, A1, LV)                                          \
  {                                                                          \
    A0 = *(const f16x8*)&(QP)[quad * 8];                                     \
    A1 = *(const f16x8*)&(QP)[32 + quad * 8];                                \
    LV = *(const float4*)(LAP);                                              \
  }

#define COMPUTE1(BUF, A0, A1, LV)                                            \
  {                                                                          \
    const f32x4 cinit = {LV.x, LV.y, LV.z, LV.w};                            \
    _Pragma("unroll") for (int c = 0; c < 4; ++c) {                          \
      f16x8 b0 = *(const f16x8*)&(BUF)[(c * 16 + lr) * 64 + ph0];            \
      f16x8 b1 = *(const f16x8*)&(BUF)[(c * 16 + lr) * 64 + ph1];            \
      f32x4 acc = cinit; /* la folded into MFMA C operand */                 \
      acc = __builtin_amdgcn_mfma_f32_16x16x32_f16(A0, b0, acc, 0, 0, 0);    \
      acc = __builtin_amdgcn_mfma_f32_16x16x32_f16(A1, b1, acc, 0, 0, 0);    \
      mx01 = fmaxf(fmaxf(acc[0], acc[1]), mx01); /* v_max3 */                \
      mx23 = fmaxf(fmaxf(acc[2], acc[3]), mx23);                             \
      asum[c][0] += __builtin_amdgcn_exp2f(acc[0]);                          \
      asum[c][1] += __builtin_amdgcn_exp2f(acc[1]);                          \
      asum[c][2] += __builtin_amdgcn_exp2f(acc[2]);                          \
      asum[c][3] += __builtin_amdgcn_exp2f(acc[3]);                          \
    }                                                                        \
  }

  const _Float16* kp = K + (size_t)(b * NH) * hstep + (size_t)k0 * DK;
  const _Float16* qp = Q + qbase;
  const float* lap = la + dbase;
  STAGE1(kp, KS);          // stage 0 -> buf 0
  kp += hstep;
  STAGE1(kp, KS + 4096);   // stage 1 -> buf 1
  kp += hstep;
  LOADQ1(qp, lap, a0c, a1c, lavc);
  qp += hstep; lap += SDIM;
  int cb = 0;
#pragma unroll 1
  for (int h = 0; h < NH; ++h) {
    if (h + 2 < NH) {
      STAGE1(kp, KS + ((cb + 2) & 3) * 4096);
      kp += hstep;
    }
    if (h + 1 < NH) {
      LOADQ1(qp, lap, a0n, a1n, lavn);
      qp += hstep; lap += SDIM;
    }
    asm volatile("" ::: "memory");
    if (h == NH - 1)
      asm volatile("s_waitcnt vmcnt(6)" ::: "memory"); // stage 15 landed
    else
      asm volatile("s_waitcnt vmcnt(10)" ::: "memory"); // stage h landed
    __builtin_amdgcn_s_barrier();
    asm volatile("" ::: "memory");
    __builtin_amdgcn_s_setprio(1);
    COMPUTE1(KS + cb * 4096, a0c, a1c, lavc);
    __builtin_amdgcn_s_setprio(0);
    if (h + 1 < NH) {
      a0c = a0n; a1c = a1n; lavc = lavn;
    }
    cb = (cb + 1) & 3;
  }
#undef STAGE1
#undef LOADQ1
#undef COMPUTE1

  const float mx = fmaxf(mx01, mx23);
  if (__any(mx >= L01)) { // cold: recompute everything with direct loads
    float amask[4][4] = {};
#pragma unroll 1
    for (int h = 0; h < NH; ++h) {
      const _Float16* Kp =
          K + (size_t)(b * NH + h) * hstep + (size_t)k0 * DK;
      const size_t ho = (size_t)h * hstep;
      const f16x8 aq0 = *(const f16x8*)&Q[qbase + ho + quad * 8];
      const f16x8 aq1 = *(const f16x8*)&Q[qbase + ho + 32 + quad * 8];
      const float4 l4 = *(const float4*)&la[dbase + (size_t)h * SDIM];
      const float lar[4] = {l4.x, l4.y, l4.z, l4.w};
#pragma unroll 1
      for (int c = 0; c < 4; ++c) {
        const f16x8 b0 = *(const f16x8*)&Kp[(c * 16 + lr) * DK + quad * 8];
        const f16x8 b1 = *(const f16x8*)&Kp[(c * 16 + lr) * DK + 32 + quad * 8];
        f32x4 acc = {0.f, 0.f, 0.f, 0.f};
        acc = __builtin_amdgcn_mfma_f32_16x16x32_f16(aq0, b0, acc, 0, 0, 0);
        acc = __builtin_amdgcn_mfma_f32_16x16x32_f16(aq1, b1, acc, 0, 0, 0);
#pragma unroll 1
        for (int r = 0; r < 4; ++r) {
          const float p = __builtin_amdgcn_exp2f(acc[r] + lar[r]);
          if (p >= 0.1f) {
            amask[c][r] += 1.0f;
            int idx = atomicAdd(ecnt, 1);
            if (idx < MAXEV)
              ev[idx] = make_float4(
                  __int_as_float(b * NH + h),
                  __int_as_float(q0 + wave * 16 + quad * 4 + r),
                  __int_as_float(k0 + c * 16 + lr), p);
          }
        }
      }
    }
    // sparse attMask writes: only the nonzero entries (rest are memset 0)
#pragma unroll
    for (int c = 0; c < 4; ++c)
#pragma unroll
      for (int r = 0; r < 4; ++r)
        if (amask[c][r] != 0.0f) {
          const size_t row = (size_t)(b * SDIM) + q0 + wave * 16 + quad * 4 + r;
          attMask[row * SDIM + k0 + c * 16 + lr] = amask[c][r];
        }
  }
  // epilogue (attSum only): LDS transpose -> full-128B-line nt stores.
  const int g8 = t >> 3;       // 0..31: row within a 32-row half
  const int l8 = (t & 7) * 4;  // float col within the 128B line
  __syncthreads(); // all waves done with K-buffer LDS reads; KS -> Tbuf
#pragma unroll
  for (int c = 0; c < 4; ++c)
#pragma unroll
    for (int r = 0; r < 4; ++r)
      Tbuf[(wave * 16 + quad * 4 + r) * 68 + c * 16 + lr] = asum[c][r];
  __syncthreads();
#pragma unroll
  for (int p = 0; p < 2; ++p)
#pragma unroll
    for (int qh = 0; qh < 2; ++qh) {
      const int row = p * 32 + g8, col = qh * 32 + l8;
      f32x4 v = *(const f32x4*)&Tbuf[row * 68 + col];
      __builtin_nontemporal_store(
          v, (f32x4*)&attSum[((size_t)(b * SDIM) + q0 + row) * SDIM + k0 + col]);
    }
}

// ---------- K3b: apply rare events to merged ctx ----------
__global__ __launch_bounds__(64) void apply_events(
    const float4* __restrict__ ev, const int* __restrict__ ecnt,
    const float* __restrict__ V, float* __restrict__ merged,
    int* __restrict__ flags) {
  int n = *ecnt;
  if (n > MAXEV) n = MAXEV;
  const int d = threadIdx.x;
  for (int e = blockIdx.x; e < n; e += gridDim.x) {
    float4 r = ev[e];
    int bh = __float_as_int(r.x);
    int q = __float_as_int(r.y);
    int kc = __float_as_int(r.z);
    float p = r.w;
    int b = bh >> 4, h = bh & 15;
    atomicAdd(&merged[((size_t)(b * SDIM + q)) * DDIM + h * DK + d],
              p * V[((size_t)bh * SDIM + kc) * DK + d]);
    if (d == 0) flags[b * SDIM + q] = 1;
  }
}

// ---------- K4: output projection with all-zero-row-tile skip ----------
__global__ __launch_bounds__(256) void out_gemm(const float* __restrict__ A,
                                                const float* __restrict__ W,
                                                const float* __restrict__ bias,
                                                float* __restrict__ out,
                                                const int* __restrict__ flags) {
  __shared__ float As[16][68];
  __shared__ float Ws[16][68];
  __shared__ int anyF;
  const int t = threadIdx.x;
  const int tx = t & 15, ty = t >> 4;
  const int m0 = blockIdx.y * 64;
  const int n0 = blockIdx.x * 64;
  if (t == 0) anyF = 0;
  __syncthreads();
  if (t < 64 && flags[m0 + t]) anyF = 1;
  __syncthreads();
  const int nb = n0 + tx * 4;
  const float4 bv = *(const float4*)&bias[nb];
  if (!anyF) {
#pragma unroll
    for (int r = 0; r < 4; ++r)
      *(float4*)&out[(size_t)(m0 + ty * 4 + r) * DDIM + nb] = bv;
    return;
  }
  const int lr = t >> 2;
  const int lc = (t & 3) * 4;
  float acc[4][4] = {};
  for (int k0 = 0; k0 < DDIM; k0 += 16) {
    __syncthreads();
    float4 av = *(const float4*)&A[(size_t)(m0 + lr) * DDIM + k0 + lc];
    float4 wv = *(const float4*)&W[(size_t)(n0 + lr) * DDIM + k0 + lc];
    As[lc + 0][lr] = av.x; As[lc + 1][lr] = av.y;
    As[lc + 2][lr] = av.z; As[lc + 3][lr] = av.w;
    Ws[lc + 0][lr] = wv.x; Ws[lc + 1][lr] = wv.y;
    Ws[lc + 2][lr] = wv.z; Ws[lc + 3][lr] = wv.w;
    __syncthreads();
#pragma unroll
    for (int kk = 0; kk < 16; ++kk) {
      float4 a4 = *(const float4*)&As[kk][ty * 4];
      float4 b4 = *(const float4*)&Ws[kk][tx * 4];
      const float a[4] = {a4.x, a4.y, a4.z, a4.w};
      const float b[4] = {b4.x, b4.y, b4.z, b4.w};
#pragma unroll
      for (int r = 0; r < 4; ++r)
#pragma unroll
        for (int c = 0; c < 4; ++c)
          acc[r][c] = fmaf(a[r], b[c], acc[r][c]);
    }
  }
#pragma unroll
  for (int r = 0; r < 4; ++r) {
    float4 o;
    o.x = acc[r][0] + bv.x;
    o.y = acc[r][1] + bv.y;
    o.z = acc[r][2] + bv.z;
    o.w = acc[r][3] + bv.w;
    *(float4*)&out[(size_t)(m0 + ty * 4 + r) * DDIM + nb] = o;
  }
}

// ---------- launcher ----------
extern "C" void kernel_launch(void* const* d_in, const int* in_sizes, int n_in,
                              void* d_out, int out_size, void* d_ws,
                              size_t ws_size, hipStream_t stream) {
  const float* x = (const float*)d_in[0];
  const float* Wq = (const float*)d_in[1];
  const float* bq = (const float*)d_in[2];
  const float* Wk = (const float*)d_in[3];
  const float* bk = (const float*)d_in[4];
  const float* Wv = (const float*)d_in[5];
  const float* bv = (const float*)d_in[6];
  const float* Wo = (const float*)d_in[7];
  const float* bo = (const float*)d_in[8];

  float* out = (float*)d_out;
  float* attSum = out + (size_t)MROWS * DDIM;
  float* attMask = attSum + (size_t)NB * SDIM * SDIM;

  char* ws = (char*)d_ws;
  const size_t bigF = (size_t)MROWS * DDIM * sizeof(float);    // 16.78 MB
  const size_t bigH = (size_t)MROWS * DDIM * sizeof(_Float16); // 8.39 MB
  const size_t wH = (size_t)DDIM * DDIM * sizeof(_Float16);    // 2.10 MB
  _Float16* Qh = (_Float16*)ws;  ws += bigH;
  _Float16* Kh = (_Float16*)ws;  ws += bigH;
  float* V = (float*)ws;         ws += bigF;
  float* merged = (float*)ws;    ws += bigF;
  _Float16* xh = (_Float16*)ws;  ws += bigH;
  _Float16* Wqh = (_Float16*)ws; ws += wH;
  _Float16* Wkh = (_Float16*)ws; ws += wH;
  _Float16* Wvh = (_Float16*)ws; ws += wH;
  float* laBuf = (float*)ws;     ws += (size_t)NB * NH * SDIM * sizeof(float);
  float4* ev = (float4*)ws;      ws += (size_t)MAXEV * sizeof(float4);
  int* flags = (int*)ws;         ws += (size_t)MROWS * sizeof(int);
  int* ecnt = (int*)ws;          ws += 16;

  hipMemsetAsync(merged, 0, bigF, stream);
  hipMemsetAsync(flags, 0, (size_t)MROWS * sizeof(int), stream);
  hipMemsetAsync(ecnt, 0, 16, stream);
  // attMask is written sparsely by attn_pass2's cold path only
  hipMemsetAsync(attMask, 0, (size_t)NB * SDIM * SDIM * sizeof(float), stream);

  dim3 blk(256);
  cvt_f16<<<dim3(7168), blk, 0, stream>>>(x, Wq, Wk, Wv, xh, Wqh, Wkh, Wvh);
  proj_gemm<<<dim3(8, 32, 3), blk, 0, stream>>>(xh, Wqh, Wkh, Wvh, bq, bk, bv,
                                                Qh, Kh, V);
  attn_denom<<<dim3(1024), blk, 0, stream>>>(Qh, Kh, laBuf);
  attn_pass2<<<dim3(2048), blk, 0, stream>>>(Qh, Kh, laBuf, attSum,
                                             attMask, ev, ecnt);
  apply_events<<<dim3(256), dim3(64), 0, stream>>>(ev, ecnt, V, merged, flags);
  out_gemm<<<dim3(16, 64), blk, 0, stream>>>(merged, Wo, bo, out, flags);
}